// Round 9
// baseline (498.657 us; speedup 1.0000x reference)
//
#include <hip/hip_runtime.h>
#include <stdint.h>

#define NN 2048
#define EE 65536
#define APITCH 360              // LDS K-pitch: 352 used + pad; 720B rows -> 2-way bank alias only
#define XSN ((size_t)NN*4096)   // elems per XS matrix [N][64][64]
#define XIN ((size_t)NN*128)    // elems per XI matrix [N][64][2]

typedef unsigned short u16;
typedef __bf16 bf16x8 __attribute__((ext_vector_type(8)));
typedef float f32x4 __attribute__((ext_vector_type(4)));
typedef float f32x2 __attribute__((ext_vector_type(2)));

__device__ __forceinline__ float bf2f(u16 h){ return __uint_as_float(((unsigned)h)<<16); }
__device__ __forceinline__ u16 f2bf(float f){
  unsigned u = __float_as_uint(f);
  u += 0x7fffu + ((u>>16)&1u);
  return (u16)(u>>16);
}
__device__ __forceinline__ float loadf(const void* p, size_t i, int bfflag){
  return bfflag ? bf2f(((const u16*)p)[i]) : ((const float*)p)[i];
}
__device__ __forceinline__ f32x2 up2(unsigned u){
  f32x2 r; r.x = __uint_as_float(u<<16); r.y = __uint_as_float(u & 0xffff0000u); return r;
}
__device__ __forceinline__ unsigned pk2(f32x2 t){
  return (unsigned)f2bf(t.x) | ((unsigned)f2bf(t.y)<<16);
}
__device__ __forceinline__ void accv(float v, uint4 d, f32x2* a){
  f32x2 vv = {v, v};
  a[0] += vv*up2(d.x); a[1] += vv*up2(d.y);
  a[2] += vv*up2(d.z); a[3] += vv*up2(d.w);
}

// dtype probe: vals1 ~ U[0,1/32). bf16 -> every u16 in [0x2800,0x3D80); f32 low-u16 ~uniform.
__global__ void probe_k(const unsigned* __restrict__ vals, int* __restrict__ flag){
  int i = threadIdx.x;
  unsigned lo = vals[i] & 0xffffu;
  unsigned long long m = __ballot(lo >= 0x2800u && lo < 0x3D80u);
  if (i==0) *flag = (__popcll(m) >= 32) ? 1 : 0;
}

__global__ void hist2_k(const int* __restrict__ e1, const int* __restrict__ e2,
                        int* __restrict__ cnt){
  int b = blockIdx.x;
  if (b < 256) atomicAdd(&cnt[e1[b*256 + threadIdx.x]], 1);
  else atomicAdd(&cnt[2048 + e2[(b-256)*256 + threadIdx.x]], 1);
}

__global__ void scan2_k(const int* __restrict__ cntA, int* __restrict__ rpA, int* __restrict__ curA){
  __shared__ int s[1024];
  const int* cnt = cntA + blockIdx.x*2048;
  int* rp  = rpA  + blockIdx.x*2049;
  int* cur = curA + blockIdx.x*2048;
  int t = threadIdx.x;
  int c0 = cnt[2*t], c1 = cnt[2*t+1];
  int ps = c0 + c1;
  s[t] = ps;
  __syncthreads();
  for (int off=1; off<1024; off<<=1){
    int v = (t>=off) ? s[t-off] : 0;
    __syncthreads();
    s[t] += v;
    __syncthreads();
  }
  int excl = s[t] - ps;
  rp[2*t] = excl;  cur[2*t] = excl;
  rp[2*t+1] = excl + c0;  cur[2*t+1] = excl + c0;
  if (t==0) rp[2048] = EE;
}

// scv.x = col*8192 (byte offset of XS row); scv.y = f32 bits of edge value.
__global__ void scatter2_k(const int* __restrict__ e1, const void* __restrict__ v1,
                           const int* __restrict__ e2, const void* __restrict__ v2,
                           int* __restrict__ curA, int2* __restrict__ scvA,
                           const int* __restrict__ flag){
  int bfflag = *flag;
  int b = blockIdx.x;
  const int* rows; const int* cols; const void* vals; int* cur; int2* scv; int e;
  if (b < 256){ rows=e1; cols=e1+EE; vals=v1; cur=curA; scv=scvA; e=b*256+threadIdx.x; }
  else { rows=e2; cols=e2+EE; vals=v2; cur=curA+2048; scv=scvA+EE; e=(b-256)*256+threadIdx.x; }
  int r = rows[e];
  int p = atomicAdd(&cur[r], 1);
  int2 cv; cv.x = cols[e] << 13; cv.y = __float_as_int(loadf(vals, e, bfflag));
  scv[p] = cv;
}

// Pack W into MFMA B-frag order. Physical K order (state-first):
//   kk in [0,320): m = kk>>6, logical f = (kk&63)+2   (state features)
//   kk in [320,330): t = kk-320, m = t>>1, f = t&1     (input features)
//   kk in [330,352): zero pad
// Wf[((q*OT+t)*64 + L)*8 + j], o = t*16+(L&15), kk = q*32+(L>>4)*8+j
__global__ void pack2_k(const void* __restrict__ Wg, const void* __restrict__ Wc,
                        u16* __restrict__ Wfg, u16* __restrict__ Wfc,
                        const int* __restrict__ flag){
  int bfflag = *flag;
  int b = blockIdx.x;
  const void* W; u16* Wf; int O, OT, i;
  if (b < 176){ W=Wg; Wf=Wfg; O=128; OT=8; i=b*256+threadIdx.x; }
  else { W=Wc; Wf=Wfc; O=64; OT=4; i=(b-176)*256+threadIdx.x; }
  int j = i & 7, L = (i>>3)&63, tq = i>>9;
  int t = tq % OT, q = tq / OT;
  int o = t*16 + (L&15);
  int kk = q*32 + (L>>4)*8 + j;
  float v = 0.f;
  if (kk < 320){ int m = kk>>6, f = (kk&63)+2; v = loadf(W, (size_t)(f*5+m)*O + o, bfflag); }
  else if (kk < 330){ int tt = kk-320; int m = tt>>1, f = tt&1; v = loadf(W, (size_t)(f*5+m)*O + o, bfflag); }
  Wf[i] = f2bf(v);
}

__global__ void build_x0_k(const void* __restrict__ inp, const void* __restrict__ st,
                           u16* __restrict__ XSb, u16* __restrict__ XIb,
                           const int* __restrict__ flag){
  int bfflag = *flag, n = blockIdx.x, tid = threadIdx.x;
  if (bfflag){
    const uint4* sp = (const uint4*)st;
    uint4* xp = (uint4*)(XSb + (size_t)n*4096);
    #pragma unroll
    for (int it=0; it<2; ++it){
      int r = tid + it*256;     // [0,512): b = r>>3, v4 = r&7
      int b = r>>3, v4 = r&7;
      xp[r] = sp[(size_t)b*(NN*8) + (size_t)n*8 + v4];
    }
    if (tid < 64){
      ((unsigned*)XIb)[n*64 + tid] = ((const unsigned*)inp)[(size_t)tid*NN + n];
    }
  } else {
    for (int i=tid; i<4096; i+=256){
      int b=i>>6, f=i&63;
      XSb[(size_t)n*4096+i] = f2bf(((const float*)st)[(size_t)b*(NN*64) + n*64 + f]);
    }
    for (int i=tid; i<128; i+=256){
      int b=i>>1, f=i&1;
      XIb[(size_t)n*128+i] = f2bf(((const float*)inp)[(size_t)b*(NN*2) + n*2 + f]);
    }
  }
}

// Diffusion hop for BOTH supports (sup = blockIdx.y).
// CHEB=0: X_dst = S X0        (src m=0, dst m = sup?3:1)
// CHEB=1: X_dst = 2 S X_src - X0  (src m = sup?3:1, dst m = sup?4:2)
// XS part: 256-thr blocks; 4 waves = 4 nodes, SAME chunk (ch = bx&7 -> XCD pin).
// bx in [0, NN*2): ch = bx&7, node = (bx>>3)*4 + wave.
// XI part: bx in [NN*2, NN*2+NN/8): 8 nodes/block, half-wave each.
template<int CHEB>
__global__ __launch_bounds__(256) void spmm_k(
    u16* __restrict__ XSb, u16* __restrict__ XIb,
    const int* __restrict__ rpA, const int2* __restrict__ scvA){
  int sup = blockIdx.y;
  const int* rp = rpA + sup*2049;
  const int2* scv = scvA + sup*EE;
  const int srcm = CHEB ? (sup?3:1) : 0;
  const int dstm = CHEB ? (sup?4:2) : (sup?3:1);
  int tid = threadIdx.x;
  int bx = blockIdx.x;
  if (bx < NN*2){
    int ch = bx & 7, w = tid >> 6, lane = tid & 63;
    int n = (bx >> 3)*4 + w;
    int e0 = rp[n], e1 = rp[n+1];
    unsigned offB = (unsigned)(ch*64 + lane)*16;
    const char* srcp = (const char*)(XSb + (size_t)srcm*XSN) + offB;
    f32x2 a[4] = {{0.f,0.f},{0.f,0.f},{0.f,0.f},{0.f,0.f}};
    int e = e0;
    if ((e & 1) && e < e1){
      int2 c = scv[e];
      accv(__int_as_float(c.y), *(const uint4*)(srcp + (unsigned)c.x), a);
      ++e;
    }
    for (; e+7 < e1; e += 8){
      const int4* s4 = (const int4*)(scv + e);   // e even -> 16B aligned
      int4 p0 = s4[0], p1 = s4[1], p2 = s4[2], p3 = s4[3];
      uint4 d0 = *(const uint4*)(srcp + (unsigned)p0.x);
      uint4 d1 = *(const uint4*)(srcp + (unsigned)p0.z);
      uint4 d2 = *(const uint4*)(srcp + (unsigned)p1.x);
      uint4 d3 = *(const uint4*)(srcp + (unsigned)p1.z);
      uint4 d4 = *(const uint4*)(srcp + (unsigned)p2.x);
      uint4 d5 = *(const uint4*)(srcp + (unsigned)p2.z);
      uint4 d6 = *(const uint4*)(srcp + (unsigned)p3.x);
      uint4 d7 = *(const uint4*)(srcp + (unsigned)p3.z);
      accv(__int_as_float(p0.y), d0, a);
      accv(__int_as_float(p0.w), d1, a);
      accv(__int_as_float(p1.y), d2, a);
      accv(__int_as_float(p1.w), d3, a);
      accv(__int_as_float(p2.y), d4, a);
      accv(__int_as_float(p2.w), d5, a);
      accv(__int_as_float(p3.y), d6, a);
      accv(__int_as_float(p3.w), d7, a);
    }
    for (; e < e1; ++e){
      int2 c = scv[e];
      accv(__int_as_float(c.y), *(const uint4*)(srcp + (unsigned)c.x), a);
    }
    unsigned doff = ((unsigned)n << 13) + offB;
    uint4* q = (uint4*)((char*)(XSb + (size_t)dstm*XSN) + doff);
    uint4 wv;
    if (CHEB){
      uint4 o = *(const uint4*)((const char*)XSb + doff);  // X0
      f32x2 t;
      t = 2.f*a[0] - up2(o.x); wv.x = pk2(t);
      t = 2.f*a[1] - up2(o.y); wv.y = pk2(t);
      t = 2.f*a[2] - up2(o.z); wv.z = pk2(t);
      t = 2.f*a[3] - up2(o.w); wv.w = pk2(t);
    } else {
      wv.x = pk2(a[0]); wv.y = pk2(a[1]); wv.z = pk2(a[2]); wv.w = pk2(a[3]);
    }
    *q = wv;
  } else {
    // XI: 8 nodes per 256-thr block, half-wave (32 lanes) per node; 32 uint2/row.
    int n = (bx - NN*2)*8 + (tid>>5), m = tid & 31;
    int e0 = rp[n], e1 = rp[n+1];
    const char* srcp = (const char*)(XIb + (size_t)srcm*XIN) + m*8;
    f32x2 a0 = {0.f,0.f}, a1 = {0.f,0.f};
    for (int e=e0; e<e1; ++e){
      int2 cv = scv[e];
      uint2 d = *(const uint2*)(srcp + ((unsigned)cv.x >> 5));  // col*256
      f32x2 vv = {__int_as_float(cv.y), __int_as_float(cv.y)};
      a0 += vv*up2(d.x); a1 += vv*up2(d.y);
    }
    unsigned doff = (unsigned)n*256 + m*8;
    if (CHEB){
      uint2 o = *(const uint2*)((const char*)XIb + doff);
      a0 = 2.f*a0 - up2(o.x); a1 = 2.f*a1 - up2(o.y);
    }
    uint2 wv; wv.x = pk2(a0); wv.y = pk2(a1);
    *(uint2*)((char*)(XIb + (size_t)dstm*XIN) + doff) = wv;
  }
}

// Block = 256 thr (4 waves), one node n per block. A(n) staged to LDS once
// (5 contiguous 8KB XS chunks + XI), physical K = m*64+f_state | 320+2m+c | pad.
// W-frags split across waves: wave w owns output tiles t = w + 4*i (i<TW=OT/4).
// MODE 0 (gate): tile i=0 (o<64) -> r*state into XS0; i=1 -> u into d_out.
// MODE 1 (cand): c = tanh; new_state = u*state + (1-u)*c into d_out.
template<int OT, int MODE>
__global__ __launch_bounds__(256) void gemm_k(
    u16* __restrict__ XSb, const u16* __restrict__ XIb,
    const u16* __restrict__ Wf, const void* __restrict__ bias,
    const void* __restrict__ state, void* __restrict__ outp,
    const int* __restrict__ flag){
  __shared__ __align__(16) u16 A[64*APITCH];
  int tid = threadIdx.x, n = blockIdx.x;
  int bfflag = *flag;
  #pragma unroll
  for (int m=0;m<5;m++){
    const uint4* src = (const uint4*)(XSb + (size_t)m*XSN + ((size_t)n<<12));
    #pragma unroll
    for (int it=0; it<2; ++it){
      int r = tid + it*256;          // 512 uint4: b = r>>3, f0 = (r&7)*8
      uint4 d = src[r];
      int b = r>>3, f0 = (r&7)*8;
      *(uint4*)&A[b*APITCH + m*64 + f0] = d;
    }
  }
  for (int i=tid; i<320; i+=256){
    int m = i>>6, b = i&63;
    unsigned v = ((const unsigned*)XIb)[(size_t)m*(XIN/2) + n*64 + b];
    *(unsigned*)&A[b*APITCH + 320 + 2*m] = v;
  }
  for (int i=tid; i<64*15; i+=256){
    int b = i/15, j = i - b*15;
    *(unsigned*)&A[b*APITCH + 330 + 2*j] = 0;
  }
  const int TW = OT/4;
  int lane = tid & 63, w = tid >> 6;
  int m16 = lane & 15, q4 = lane >> 4;
  const bf16x8* wp = (const bf16x8*)Wf;
  bf16x8 wfr[11][TW];
  #pragma unroll
  for (int q=0;q<11;q++){
    #pragma unroll
    for (int i=0;i<TW;i++) wfr[q][i] = wp[(q*OT + (w + 4*i))*64 + lane];
  }
  __syncthreads();
  #pragma unroll
  for (int rt4=0; rt4<4; ++rt4){
    const u16* arow = A + (rt4*16 + m16)*APITCH + q4*8;
    f32x4 acc[TW];
    #pragma unroll
    for (int i=0;i<TW;i++) acc[i] = (f32x4){0.f,0.f,0.f,0.f};
    #pragma unroll
    for (int q=0;q<11;q++){
      bf16x8 af = *((const bf16x8*)(arow + q*32));
      #pragma unroll
      for (int i=0;i<TW;i++)
        acc[i] = __builtin_amdgcn_mfma_f32_16x16x32_bf16(af, wfr[q][i], acc[i], 0, 0, 0);
    }
    #pragma unroll
    for (int i=0;i<TW;i++){
      int t = w + 4*i;
      int o = t*16 + m16;
      float bo = loadf(bias, o, bfflag);
      #pragma unroll
      for (int r=0;r<4;r++){
        int b = rt4*16 + q4*4 + r;
        float x = acc[i][r] + bo;
        if (MODE==0){
          float s = 1.f/(1.f + __expf(-x));
          if (i==0){   // o < 64: r-gate -> r*state overwrites XS0(n)
            float st = loadf(state, (size_t)b*(NN*64) + (size_t)n*64 + o, bfflag);
            XSb[((size_t)n<<12) + b*64 + o] = f2bf(s*st);
          } else {     // o >= 64: u stashed in d_out
            size_t idx = (size_t)b*(NN*64) + (size_t)n*64 + (o-64);
            if (bfflag) ((u16*)outp)[idx] = f2bf(s); else ((float*)outp)[idx] = s;
          }
        } else {
          float c = tanhf(x);
          size_t idx = (size_t)b*(NN*64) + (size_t)n*64 + o;
          float uu = bfflag ? bf2f(((const u16*)outp)[idx]) : ((const float*)outp)[idx];
          float st = loadf(state, idx, bfflag);
          float ns = uu*st + (1.f-uu)*c;
          if (bfflag) ((u16*)outp)[idx] = f2bf(ns); else ((float*)outp)[idx] = ns;
        }
      }
    }
  }
}

extern "C" void kernel_launch(void* const* d_in, const int* in_sizes, int n_in,
                              void* d_out, int out_size, void* d_ws, size_t ws_size,
                              hipStream_t stream) {
  const void* inputs = d_in[0];
  const void* state  = d_in[1];
  const int* edges1 = (const int*)d_in[2];
  const void* vals1  = d_in[3];
  const int* edges2 = (const int*)d_in[4];
  const void* vals2  = d_in[5];
  const void* Wg     = d_in[6];
  const void* bg     = d_in[7];
  const void* Wc     = d_in[8];
  const void* bc     = d_in[9];

  char* ws = (char*)d_ws;
  size_t off = 0;
  auto get = [&](size_t bytes)->void*{
    void* p = ws + off; off = (off + bytes + 255) & ~(size_t)255; return p;
  };
  u16* XSb = (u16*)get(5*XSN*2);   // 83.9 MB
  u16* XIb = (u16*)get(5*XIN*2);   // 2.6 MB
  u16* Wfg = (u16*)get(11*8*64*8*2);
  u16* Wfc = (u16*)get(11*4*64*8*2);
  int* cnt  = (int*)get(2*2048*4);
  int* rp   = (int*)get(2*2049*4);
  int* cur  = (int*)get(2*2048*4);
  int* flag = (int*)get(4);
  int2* scv = (int2*)get((size_t)2*EE*8);

  probe_k<<<1,64,0,stream>>>((const unsigned*)vals1, flag);
  hipMemsetAsync(cnt, 0, 2*2048*4, stream);
  hist2_k<<<512,256,0,stream>>>(edges1, edges2, cnt);
  scan2_k<<<2,1024,0,stream>>>(cnt, rp, cur);
  scatter2_k<<<512,256,0,stream>>>(edges1, vals1, edges2, vals2, cur, scv, flag);
  pack2_k<<<264,256,0,stream>>>(Wg, Wc, Wfg, Wfc, flag);
  build_x0_k<<<NN,256,0,stream>>>(inputs, state, XSb, XIb, flag);

  dim3 sg(NN*2 + NN/8, 2);
  // gate diffusion
  spmm_k<0><<<sg,256,0,stream>>>(XSb, XIb, rp, scv);
  spmm_k<1><<<sg,256,0,stream>>>(XSb, XIb, rp, scv);
  gemm_k<8,0><<<NN,256,0,stream>>>(XSb, XIb, Wfg, bg, state, d_out, flag);
  // candidate diffusion (XS0 now = r*state, XI0 = inputs)
  spmm_k<0><<<sg,256,0,stream>>>(XSb, XIb, rp, scv);
  spmm_k<1><<<sg,256,0,stream>>>(XSb, XIb, rp, scv);
  gemm_k<4,1><<<NN,256,0,stream>>>(XSb, XIb, Wfc, bc, state, d_out, flag);
}

// Round 11
// 482.843 us; speedup vs baseline: 1.0328x; 1.0328x over previous
//
#include <hip/hip_runtime.h>
#include <stdint.h>

#define NN 2048
#define EE 65536
#define APITCH 360              // LDS K-pitch: 352 used + pad; 720B rows -> 2-way bank alias only
#define XSN ((size_t)NN*4096)   // elems per XS matrix [N][64][64]
#define XIN ((size_t)NN*128)    // elems per XI matrix [N][64][2]

typedef unsigned short u16;
typedef __bf16 bf16x8 __attribute__((ext_vector_type(8)));
typedef float f32x4 __attribute__((ext_vector_type(4)));
typedef float f32x2 __attribute__((ext_vector_type(2)));
typedef unsigned u32x4 __attribute__((ext_vector_type(4)));   // NT-capable 16B vector

__device__ __forceinline__ float bf2f(u16 h){ return __uint_as_float(((unsigned)h)<<16); }
__device__ __forceinline__ u16 f2bf(float f){
  unsigned u = __float_as_uint(f);
  u += 0x7fffu + ((u>>16)&1u);
  return (u16)(u>>16);
}
__device__ __forceinline__ float loadf(const void* p, size_t i, int bfflag){
  return bfflag ? bf2f(((const u16*)p)[i]) : ((const float*)p)[i];
}
__device__ __forceinline__ f32x2 up2(unsigned u){
  f32x2 r; r.x = __uint_as_float(u<<16); r.y = __uint_as_float(u & 0xffff0000u); return r;
}
__device__ __forceinline__ unsigned pk2(f32x2 t){
  return (unsigned)f2bf(t.x) | ((unsigned)f2bf(t.y)<<16);
}
__device__ __forceinline__ void accv(float v, u32x4 d, f32x2* a){
  f32x2 vv = {v, v};
  a[0] += vv*up2(d.x); a[1] += vv*up2(d.y);
  a[2] += vv*up2(d.z); a[3] += vv*up2(d.w);
}

// dtype probe: vals1 ~ U[0,1/32). bf16 -> every u16 in [0x2800,0x3D80); f32 low-u16 ~uniform.
__global__ void probe_k(const unsigned* __restrict__ vals, int* __restrict__ flag){
  int i = threadIdx.x;
  unsigned lo = vals[i] & 0xffffu;
  unsigned long long m = __ballot(lo >= 0x2800u && lo < 0x3D80u);
  if (i==0) *flag = (__popcll(m) >= 32) ? 1 : 0;
}

__global__ void hist2_k(const int* __restrict__ e1, const int* __restrict__ e2,
                        int* __restrict__ cnt){
  int b = blockIdx.x;
  if (b < 256) atomicAdd(&cnt[e1[b*256 + threadIdx.x]], 1);
  else atomicAdd(&cnt[2048 + e2[(b-256)*256 + threadIdx.x]], 1);
}

__global__ void scan2_k(const int* __restrict__ cntA, int* __restrict__ rpA, int* __restrict__ curA){
  __shared__ int s[1024];
  const int* cnt = cntA + blockIdx.x*2048;
  int* rp  = rpA  + blockIdx.x*2049;
  int* cur = curA + blockIdx.x*2048;
  int t = threadIdx.x;
  int c0 = cnt[2*t], c1 = cnt[2*t+1];
  int ps = c0 + c1;
  s[t] = ps;
  __syncthreads();
  for (int off=1; off<1024; off<<=1){
    int v = (t>=off) ? s[t-off] : 0;
    __syncthreads();
    s[t] += v;
    __syncthreads();
  }
  int excl = s[t] - ps;
  rp[2*t] = excl;  cur[2*t] = excl;
  rp[2*t+1] = excl + c0;  cur[2*t+1] = excl + c0;
  if (t==0) rp[2048] = EE;
}

// scv.x = col*8192 (byte offset of XS row); scv.y = f32 bits of edge value.
__global__ void scatter2_k(const int* __restrict__ e1, const void* __restrict__ v1,
                           const int* __restrict__ e2, const void* __restrict__ v2,
                           int* __restrict__ curA, int2* __restrict__ scvA,
                           const int* __restrict__ flag){
  int bfflag = *flag;
  int b = blockIdx.x;
  const int* rows; const int* cols; const void* vals; int* cur; int2* scv; int e;
  if (b < 256){ rows=e1; cols=e1+EE; vals=v1; cur=curA; scv=scvA; e=b*256+threadIdx.x; }
  else { rows=e2; cols=e2+EE; vals=v2; cur=curA+2048; scv=scvA+EE; e=(b-256)*256+threadIdx.x; }
  int r = rows[e];
  int p = atomicAdd(&cur[r], 1);
  int2 cv; cv.x = cols[e] << 13; cv.y = __float_as_int(loadf(vals, e, bfflag));
  scv[p] = cv;
}

// Pack W into MFMA B-frag order. Physical K order (state-first):
//   kk in [0,320): m = kk>>6, logical f = (kk&63)+2   (state features)
//   kk in [320,330): t = kk-320, m = t>>1, f = t&1     (input features)
//   kk in [330,352): zero pad
// Wf[((q*OT+t)*64 + L)*8 + j], o = t*16+(L&15), kk = q*32+(L>>4)*8+j
__global__ void pack2_k(const void* __restrict__ Wg, const void* __restrict__ Wc,
                        u16* __restrict__ Wfg, u16* __restrict__ Wfc,
                        const int* __restrict__ flag){
  int bfflag = *flag;
  int b = blockIdx.x;
  const void* W; u16* Wf; int O, OT, i;
  if (b < 176){ W=Wg; Wf=Wfg; O=128; OT=8; i=b*256+threadIdx.x; }
  else { W=Wc; Wf=Wfc; O=64; OT=4; i=(b-176)*256+threadIdx.x; }
  int j = i & 7, L = (i>>3)&63, tq = i>>9;
  int t = tq % OT, q = tq / OT;
  int o = t*16 + (L&15);
  int kk = q*32 + (L>>4)*8 + j;
  float v = 0.f;
  if (kk < 320){ int m = kk>>6, f = (kk&63)+2; v = loadf(W, (size_t)(f*5+m)*O + o, bfflag); }
  else if (kk < 330){ int tt = kk-320; int m = tt>>1, f = tt&1; v = loadf(W, (size_t)(f*5+m)*O + o, bfflag); }
  Wf[i] = f2bf(v);
}

__global__ void build_x0_k(const void* __restrict__ inp, const void* __restrict__ st,
                           u16* __restrict__ XSb, u16* __restrict__ XIb,
                           const int* __restrict__ flag){
  int bfflag = *flag, n = blockIdx.x, tid = threadIdx.x;
  if (bfflag){
    const uint4* sp = (const uint4*)st;
    uint4* xp = (uint4*)(XSb + (size_t)n*4096);
    #pragma unroll
    for (int it=0; it<2; ++it){
      int r = tid + it*256;     // [0,512): b = r>>3, v4 = r&7
      int b = r>>3, v4 = r&7;
      xp[r] = sp[(size_t)b*(NN*8) + (size_t)n*8 + v4];
    }
    if (tid < 64){
      ((unsigned*)XIb)[n*64 + tid] = ((const unsigned*)inp)[(size_t)tid*NN + n];
    }
  } else {
    for (int i=tid; i<4096; i+=256){
      int b=i>>6, f=i&63;
      XSb[(size_t)n*4096+i] = f2bf(((const float*)st)[(size_t)b*(NN*64) + n*64 + f]);
    }
    for (int i=tid; i<128; i+=256){
      int b=i>>1, f=i&1;
      XIb[(size_t)n*128+i] = f2bf(((const float*)inp)[(size_t)b*(NN*2) + n*2 + f]);
    }
  }
}

// Diffusion hop for BOTH supports, folded into blockIdx.x.
// CHEB=0: X_dst = S X0        (src m=0, dst m = sup?3:1)
// CHEB=1: X_dst = 2 S X_src - X0  (src m = sup?3:1, dst m = sup?4:2)
// XS part: bx in [0, NN*8): ch = bx&3 (2KB chunk, 32B/lane), sup = (bx>>2)&1,
//   n = bx>>3. bx&7 = sup*4+ch -> XCD pin: per-XCD gather set = 4.2MB (~L2).
// XI part: bx in [NN*8, NN*9): idx=bx-NN*8, sup=idx&1, 2 nodes per 64-thr block.
// dst stores + CHEB X0 reads are non-temporal (don't evict the gather src).
template<int CHEB>
__global__ __launch_bounds__(64) void spmm_k(
    u16* __restrict__ XSb, u16* __restrict__ XIb,
    const int* __restrict__ rpA, const int2* __restrict__ scvA){
  int tid = threadIdx.x;
  int bx = blockIdx.x;
  if (bx < NN*8){
    int ch = bx & 3, sup = (bx>>2)&1, n = bx >> 3;
    const int* rp = rpA + sup*2049;
    const int2* scv = scvA + sup*EE;
    const int srcm = CHEB ? (sup?3:1) : 0;
    const int dstm = CHEB ? (sup?4:2) : (sup?3:1);
    int e0 = rp[n], e1 = rp[n+1];
    unsigned offB = (unsigned)ch*2048 + (unsigned)tid*32;
    const char* srcp = (const char*)(XSb + (size_t)srcm*XSN) + offB;
    f32x2 a[8] = {{0.f,0.f},{0.f,0.f},{0.f,0.f},{0.f,0.f},
                  {0.f,0.f},{0.f,0.f},{0.f,0.f},{0.f,0.f}};
    int e = e0;
    for (; e+1 < e1; e += 2){
      int2 c0 = scv[e], c1 = scv[e+1];
      const char* p0 = srcp + (unsigned)c0.x;
      const char* p1 = srcp + (unsigned)c1.x;
      u32x4 d00 = *(const u32x4*)p0;
      u32x4 d01 = *(const u32x4*)(p0+16);
      u32x4 d10 = *(const u32x4*)p1;
      u32x4 d11 = *(const u32x4*)(p1+16);
      float v0 = __int_as_float(c0.y), v1 = __int_as_float(c1.y);
      accv(v0, d00, a); accv(v0, d01, a+4);
      accv(v1, d10, a); accv(v1, d11, a+4);
    }
    if (e < e1){
      int2 c0 = scv[e];
      const char* p0 = srcp + (unsigned)c0.x;
      u32x4 d00 = *(const u32x4*)p0;
      u32x4 d01 = *(const u32x4*)(p0+16);
      float v0 = __int_as_float(c0.y);
      accv(v0, d00, a); accv(v0, d01, a+4);
    }
    unsigned doff = ((unsigned)n << 13) + offB;
    char* dstp = (char*)(XSb + (size_t)dstm*XSN) + doff;
    u32x4 w0, w1;
    if (CHEB){
      u32x4 o0 = __builtin_nontemporal_load((const u32x4*)((const char*)XSb + doff));
      u32x4 o1 = __builtin_nontemporal_load((const u32x4*)((const char*)XSb + doff + 16));
      f32x2 t;
      t = 2.f*a[0] - up2(o0.x); w0.x = pk2(t);
      t = 2.f*a[1] - up2(o0.y); w0.y = pk2(t);
      t = 2.f*a[2] - up2(o0.z); w0.z = pk2(t);
      t = 2.f*a[3] - up2(o0.w); w0.w = pk2(t);
      t = 2.f*a[4] - up2(o1.x); w1.x = pk2(t);
      t = 2.f*a[5] - up2(o1.y); w1.y = pk2(t);
      t = 2.f*a[6] - up2(o1.z); w1.z = pk2(t);
      t = 2.f*a[7] - up2(o1.w); w1.w = pk2(t);
    } else {
      w0.x = pk2(a[0]); w0.y = pk2(a[1]); w0.z = pk2(a[2]); w0.w = pk2(a[3]);
      w1.x = pk2(a[4]); w1.y = pk2(a[5]); w1.z = pk2(a[6]); w1.w = pk2(a[7]);
    }
    __builtin_nontemporal_store(w0, (u32x4*)dstp);
    __builtin_nontemporal_store(w1, (u32x4*)(dstp+16));
  } else {
    // XI: idx = bx - NN*8 in [0, NN): sup = idx&1, 2 nodes/block, half-wave each.
    int idx = bx - NN*8;
    int sup = idx & 1;
    const int* rp = rpA + sup*2049;
    const int2* scv = scvA + sup*EE;
    const int srcm = CHEB ? (sup?3:1) : 0;
    const int dstm = CHEB ? (sup?4:2) : (sup?3:1);
    int n = (idx>>1)*2 + (tid>>5), m = tid & 31;
    int e0 = rp[n], e1 = rp[n+1];
    const char* srcp = (const char*)(XIb + (size_t)srcm*XIN) + m*8;
    f32x2 a0 = {0.f,0.f}, a1 = {0.f,0.f};
    for (int e=e0; e<e1; ++e){
      int2 cv = scv[e];
      uint2 d = *(const uint2*)(srcp + ((unsigned)cv.x >> 5));  // col*256
      f32x2 vv = {__int_as_float(cv.y), __int_as_float(cv.y)};
      a0 += vv*up2(d.x); a1 += vv*up2(d.y);
    }
    unsigned doff = (unsigned)n*256 + m*8;
    if (CHEB){
      uint2 o = *(const uint2*)((const char*)XIb + doff);
      a0 = 2.f*a0 - up2(o.x); a1 = 2.f*a1 - up2(o.y);
    }
    uint2 wv; wv.x = pk2(a0); wv.y = pk2(a1);
    *(uint2*)((char*)(XIb + (size_t)dstm*XIN) + doff) = wv;
  }
}

// Block = 256 thr (4 waves), one node n per block. A(n) staged to LDS once
// (5 contiguous 8KB XS chunks + XI), physical K = m*64+f_state | 320+2m+c | pad.
// W-frags split across waves: wave w owns output tiles t = w + 4*i (i<TW=OT/4).
// MODE 0 (gate): tile i=0 (o<64) -> r*state into XS0; i=1 -> u into d_out.
// MODE 1 (cand): c = tanh; new_state = u*state + (1-u)*c into d_out.
template<int OT, int MODE>
__global__ __launch_bounds__(256) void gemm_k(
    u16* __restrict__ XSb, const u16* __restrict__ XIb,
    const u16* __restrict__ Wf, const void* __restrict__ bias,
    const void* __restrict__ state, void* __restrict__ outp,
    const int* __restrict__ flag){
  __shared__ __align__(16) u16 A[64*APITCH];
  int tid = threadIdx.x, n = blockIdx.x;
  int bfflag = *flag;
  #pragma unroll
  for (int m=0;m<5;m++){
    const uint4* src = (const uint4*)(XSb + (size_t)m*XSN + ((size_t)n<<12));
    #pragma unroll
    for (int it=0; it<2; ++it){
      int r = tid + it*256;          // 512 uint4: b = r>>3, f0 = (r&7)*8
      uint4 d = src[r];
      int b = r>>3, f0 = (r&7)*8;
      *(uint4*)&A[b*APITCH + m*64 + f0] = d;
    }
  }
  for (int i=tid; i<320; i+=256){
    int m = i>>6, b = i&63;
    unsigned v = ((const unsigned*)XIb)[(size_t)m*(XIN/2) + n*64 + b];
    *(unsigned*)&A[b*APITCH + 320 + 2*m] = v;
  }
  for (int i=tid; i<64*15; i+=256){
    int b = i/15, j = i - b*15;
    *(unsigned*)&A[b*APITCH + 330 + 2*j] = 0;
  }
  const int TW = OT/4;
  int lane = tid & 63, w = tid >> 6;
  int m16 = lane & 15, q4 = lane >> 4;
  const bf16x8* wp = (const bf16x8*)Wf;
  bf16x8 wfr[11][TW];
  #pragma unroll
  for (int q=0;q<11;q++){
    #pragma unroll
    for (int i=0;i<TW;i++) wfr[q][i] = wp[(q*OT + (w + 4*i))*64 + lane];
  }
  __syncthreads();
  #pragma unroll
  for (int rt4=0; rt4<4; ++rt4){
    const u16* arow = A + (rt4*16 + m16)*APITCH + q4*8;
    f32x4 acc[TW];
    #pragma unroll
    for (int i=0;i<TW;i++) acc[i] = (f32x4){0.f,0.f,0.f,0.f};
    #pragma unroll
    for (int q=0;q<11;q++){
      bf16x8 af = *((const bf16x8*)(arow + q*32));
      #pragma unroll
      for (int i=0;i<TW;i++)
        acc[i] = __builtin_amdgcn_mfma_f32_16x16x32_bf16(af, wfr[q][i], acc[i], 0, 0, 0);
    }
    #pragma unroll
    for (int i=0;i<TW;i++){
      int t = w + 4*i;
      int o = t*16 + m16;
      float bo = loadf(bias, o, bfflag);
      #pragma unroll
      for (int r=0;r<4;r++){
        int b = rt4*16 + q4*4 + r;
        float x = acc[i][r] + bo;
        if (MODE==0){
          float s = 1.f/(1.f + __expf(-x));
          if (i==0){   // o < 64: r-gate -> r*state overwrites XS0(n)
            float st = loadf(state, (size_t)b*(NN*64) + (size_t)n*64 + o, bfflag);
            XSb[((size_t)n<<12) + b*64 + o] = f2bf(s*st);
          } else {     // o >= 64: u stashed in d_out
            size_t idx = (size_t)b*(NN*64) + (size_t)n*64 + (o-64);
            if (bfflag) ((u16*)outp)[idx] = f2bf(s); else ((float*)outp)[idx] = s;
          }
        } else {
          float c = tanhf(x);
          size_t idx = (size_t)b*(NN*64) + (size_t)n*64 + o;
          float uu = bfflag ? bf2f(((const u16*)outp)[idx]) : ((const float*)outp)[idx];
          float st = loadf(state, idx, bfflag);
          float ns = uu*st + (1.f-uu)*c;
          if (bfflag) ((u16*)outp)[idx] = f2bf(ns); else ((float*)outp)[idx] = ns;
        }
      }
    }
  }
}

extern "C" void kernel_launch(void* const* d_in, const int* in_sizes, int n_in,
                              void* d_out, int out_size, void* d_ws, size_t ws_size,
                              hipStream_t stream) {
  const void* inputs = d_in[0];
  const void* state  = d_in[1];
  const int* edges1 = (const int*)d_in[2];
  const void* vals1  = d_in[3];
  const int* edges2 = (const int*)d_in[4];
  const void* vals2  = d_in[5];
  const void* Wg     = d_in[6];
  const void* bg     = d_in[7];
  const void* Wc     = d_in[8];
  const void* bc     = d_in[9];

  char* ws = (char*)d_ws;
  size_t off = 0;
  auto get = [&](size_t bytes)->void*{
    void* p = ws + off; off = (off + bytes + 255) & ~(size_t)255; return p;
  };
  u16* XSb = (u16*)get(5*XSN*2);   // 83.9 MB
  u16* XIb = (u16*)get(5*XIN*2);   // 2.6 MB
  u16* Wfg = (u16*)get(11*8*64*8*2);
  u16* Wfc = (u16*)get(11*4*64*8*2);
  int* cnt  = (int*)get(2*2048*4);
  int* rp   = (int*)get(2*2049*4);
  int* cur  = (int*)get(2*2048*4);
  int* flag = (int*)get(4);
  int2* scv = (int2*)get((size_t)2*EE*8);

  probe_k<<<1,64,0,stream>>>((const unsigned*)vals1, flag);
  hipMemsetAsync(cnt, 0, 2*2048*4, stream);
  hist2_k<<<512,256,0,stream>>>(edges1, edges2, cnt);
  scan2_k<<<2,1024,0,stream>>>(cnt, rp, cur);
  scatter2_k<<<512,256,0,stream>>>(edges1, vals1, edges2, vals2, cur, scv, flag);
  pack2_k<<<264,256,0,stream>>>(Wg, Wc, Wfg, Wfc, flag);
  build_x0_k<<<NN,256,0,stream>>>(inputs, state, XSb, XIb, flag);

  const int SG = NN*8 + NN;   // XS blocks + XI blocks (both sups folded in x)
  // gate diffusion
  spmm_k<0><<<SG,64,0,stream>>>(XSb, XIb, rp, scv);
  spmm_k<1><<<SG,64,0,stream>>>(XSb, XIb, rp, scv);
  gemm_k<8,0><<<NN,256,0,stream>>>(XSb, XIb, Wfg, bg, state, d_out, flag);
  // candidate diffusion (XS0 now = r*state, XI0 = inputs)
  spmm_k<0><<<SG,64,0,stream>>>(XSb, XIb, rp, scv);
  spmm_k<1><<<SG,64,0,stream>>>(XSb, XIb, rp, scv);
  gemm_k<4,1><<<NN,256,0,stream>>>(XSb, XIb, Wfc, bc, state, d_out, flag);
}

// Round 12
// 440.199 us; speedup vs baseline: 1.1328x; 1.0969x over previous
//
#include <hip/hip_runtime.h>
#include <stdint.h>

#define NN 2048
#define EE 65536
#define APITCH 360              // LDS K-pitch: 352 used + pad
#define XSN ((size_t)NN*4096)   // elems per XS matrix [N][64][64]
#define XIN ((size_t)NN*128)    // elems per XI matrix [N][64][2]

typedef unsigned short u16;
typedef __bf16 bf16x8 __attribute__((ext_vector_type(8)));
typedef float f32x4 __attribute__((ext_vector_type(4)));
typedef float f32x2 __attribute__((ext_vector_type(2)));
typedef unsigned u32x4 __attribute__((ext_vector_type(4)));

__device__ __forceinline__ float bf2f(u16 h){ return __uint_as_float(((unsigned)h)<<16); }
__device__ __forceinline__ u16 f2bf(float f){
  unsigned u = __float_as_uint(f);
  u += 0x7fffu + ((u>>16)&1u);
  return (u16)(u>>16);
}
__device__ __forceinline__ float loadf(const void* p, size_t i, int bfflag){
  return bfflag ? bf2f(((const u16*)p)[i]) : ((const float*)p)[i];
}
__device__ __forceinline__ f32x2 up2(unsigned u){
  f32x2 r; r.x = __uint_as_float(u<<16); r.y = __uint_as_float(u & 0xffff0000u); return r;
}
__device__ __forceinline__ unsigned pk2(f32x2 t){
  return (unsigned)f2bf(t.x) | ((unsigned)f2bf(t.y)<<16);
}
__device__ __forceinline__ void accv(float v, u32x4 d, f32x2* a){
  f32x2 vv = {v, v};
  a[0] += vv*up2(d.x); a[1] += vv*up2(d.y);
  a[2] += vv*up2(d.z); a[3] += vv*up2(d.w);
}

// Merged: block 0 = dtype probe; blocks 1..256 = hist e1; 257..512 = hist e2.
// (cnt zeroed by prior memset)
__global__ void setup1_k(const unsigned* __restrict__ vals,
                         const int* __restrict__ e1, const int* __restrict__ e2,
                         int* __restrict__ cnt, int* __restrict__ flag){
  int b = blockIdx.x, tid = threadIdx.x;
  if (b == 0){
    if (tid < 64){
      unsigned lo = vals[tid] & 0xffffu;
      unsigned long long m = __ballot(lo >= 0x2800u && lo < 0x3D80u);
      if (tid==0) *flag = (__popcll(m) >= 32) ? 1 : 0;
    }
  } else if (b <= 256){
    atomicAdd(&cnt[e1[(b-1)*256 + tid]], 1);
  } else {
    atomicAdd(&cnt[2048 + e2[(b-257)*256 + tid]], 1);
  }
}

__global__ void scan2_k(const int* __restrict__ cntA, int* __restrict__ rpA, int* __restrict__ curA){
  __shared__ int s[1024];
  const int* cnt = cntA + blockIdx.x*2048;
  int* rp  = rpA  + blockIdx.x*2049;
  int* cur = curA + blockIdx.x*2048;
  int t = threadIdx.x;
  int c0 = cnt[2*t], c1 = cnt[2*t+1];
  int ps = c0 + c1;
  s[t] = ps;
  __syncthreads();
  for (int off=1; off<1024; off<<=1){
    int v = (t>=off) ? s[t-off] : 0;
    __syncthreads();
    s[t] += v;
    __syncthreads();
  }
  int excl = s[t] - ps;
  rp[2*t] = excl;  cur[2*t] = excl;
  rp[2*t+1] = excl + c0;  cur[2*t+1] = excl + c0;
  if (t==0) rp[2048] = EE;
}

// Merged post-scan setup. Sections by blockIdx.x:
//  [0,512): scatter (scv.x = col*8192 byte offset, scv.y = f32 bits of val)
//  [512,776): pack W into MFMA B-frag order (state-first physical K)
//  [776,776+NN): build X0 (XS = state part [N][64][64], XI = input part [N][64][2])
__global__ void setup2_k(const int* __restrict__ e1, const void* __restrict__ v1,
                         const int* __restrict__ e2, const void* __restrict__ v2,
                         int* __restrict__ curA, int2* __restrict__ scvA,
                         const void* __restrict__ Wg, const void* __restrict__ Wc,
                         u16* __restrict__ Wfg, u16* __restrict__ Wfc,
                         const void* __restrict__ inp, const void* __restrict__ st,
                         u16* __restrict__ XSb, u16* __restrict__ XIb,
                         const int* __restrict__ flag){
  int b = blockIdx.x, tid = threadIdx.x;
  int bfflag = *flag;
  if (b < 512){
    const int* rows; const int* cols; const void* vals; int* cur; int2* scv; int e;
    if (b < 256){ rows=e1; cols=e1+EE; vals=v1; cur=curA; scv=scvA; e=b*256+tid; }
    else { rows=e2; cols=e2+EE; vals=v2; cur=curA+2048; scv=scvA+EE; e=(b-256)*256+tid; }
    int r = rows[e];
    int p = atomicAdd(&cur[r], 1);
    int2 cv; cv.x = cols[e] << 13; cv.y = __float_as_int(loadf(vals, e, bfflag));
    scv[p] = cv;
  } else if (b < 776){
    int bb = b - 512;
    const void* W; u16* Wf; int O, OT, i;
    if (bb < 176){ W=Wg; Wf=Wfg; O=128; OT=8; i=bb*256+tid; }
    else { W=Wc; Wf=Wfc; O=64; OT=4; i=(bb-176)*256+tid; }
    int j = i & 7, L = (i>>3)&63, tq = i>>9;
    int t = tq % OT, q = tq / OT;
    int o = t*16 + (L&15);
    int kk = q*32 + (L>>4)*8 + j;
    float v = 0.f;
    if (kk < 320){ int m = kk>>6, f = (kk&63)+2; v = loadf(W, (size_t)(f*5+m)*O + o, bfflag); }
    else if (kk < 330){ int tt = kk-320; int m = tt>>1, f = tt&1; v = loadf(W, (size_t)(f*5+m)*O + o, bfflag); }
    Wf[i] = f2bf(v);
  } else {
    int n = b - 776;
    if (bfflag){
      const uint4* sp = (const uint4*)st;
      uint4* xp = (uint4*)(XSb + (size_t)n*4096);
      #pragma unroll
      for (int it=0; it<2; ++it){
        int r = tid + it*256;     // [0,512): bb = r>>3, v4 = r&7
        int bb = r>>3, v4 = r&7;
        xp[r] = sp[(size_t)bb*(NN*8) + (size_t)n*8 + v4];
      }
      if (tid < 64){
        ((unsigned*)XIb)[n*64 + tid] = ((const unsigned*)inp)[(size_t)tid*NN + n];
      }
    } else {
      for (int i=tid; i<4096; i+=256){
        int bb=i>>6, f=i&63;
        XSb[(size_t)n*4096+i] = f2bf(((const float*)st)[(size_t)bb*(NN*64) + n*64 + f]);
      }
      for (int i=tid; i<128; i+=256){
        int bb=i>>1, f=i&1;
        XIb[(size_t)n*128+i] = f2bf(((const float*)inp)[(size_t)bb*(NN*2) + n*2 + f]);
      }
    }
  }
}

// Diffusion hop for BOTH supports (sup = blockIdx.y). R8-proven config:
// 64-thr blocks, 1KB chunks (16B/lane), ch = bx&7 -> XCD pin, 8-edge unroll.
// CHEB=0: X_dst = S X0; CHEB=1: X_dst = 2 S X_src - X0.
// XS: bx in [0, NN*8). XI: bx in [NN*8, NN*8+NN/2): 2 nodes/block, half-wave each.
template<int CHEB>
__global__ __launch_bounds__(64) void spmm_k(
    u16* __restrict__ XSb, u16* __restrict__ XIb,
    const int* __restrict__ rpA, const int2* __restrict__ scvA){
  int sup = blockIdx.y;
  const int* rp = rpA + sup*2049;
  const int2* scv = scvA + sup*EE;
  const int srcm = CHEB ? (sup?3:1) : 0;
  const int dstm = CHEB ? (sup?4:2) : (sup?3:1);
  int tid = threadIdx.x;
  int bx = blockIdx.x;
  if (bx < NN*8){
    int ch = bx & 7, n = bx >> 3;
    int e0 = rp[n], e1 = rp[n+1];
    unsigned offB = (unsigned)(ch*64 + tid)*16;
    const char* srcp = (const char*)(XSb + (size_t)srcm*XSN) + offB;
    f32x2 a[4] = {{0.f,0.f},{0.f,0.f},{0.f,0.f},{0.f,0.f}};
    int e = e0;
    for (; e+7 < e1; e += 8){
      const int4* s4 = (const int4*)(scv + e);
      int4 p0 = s4[0], p1 = s4[1], p2 = s4[2], p3 = s4[3];
      u32x4 d0 = *(const u32x4*)(srcp + (unsigned)p0.x);
      u32x4 d1 = *(const u32x4*)(srcp + (unsigned)p0.z);
      u32x4 d2 = *(const u32x4*)(srcp + (unsigned)p1.x);
      u32x4 d3 = *(const u32x4*)(srcp + (unsigned)p1.z);
      u32x4 d4 = *(const u32x4*)(srcp + (unsigned)p2.x);
      u32x4 d5 = *(const u32x4*)(srcp + (unsigned)p2.z);
      u32x4 d6 = *(const u32x4*)(srcp + (unsigned)p3.x);
      u32x4 d7 = *(const u32x4*)(srcp + (unsigned)p3.z);
      accv(__int_as_float(p0.y), d0, a);
      accv(__int_as_float(p0.w), d1, a);
      accv(__int_as_float(p1.y), d2, a);
      accv(__int_as_float(p1.w), d3, a);
      accv(__int_as_float(p2.y), d4, a);
      accv(__int_as_float(p2.w), d5, a);
      accv(__int_as_float(p3.y), d6, a);
      accv(__int_as_float(p3.w), d7, a);
    }
    for (; e < e1; ++e){
      int2 c = scv[e];
      accv(__int_as_float(c.y), *(const u32x4*)(srcp + (unsigned)c.x), a);
    }
    unsigned doff = ((unsigned)n << 13) + offB;
    u32x4 w;
    if (CHEB){
      u32x4 o = *(const u32x4*)((const char*)XSb + doff);  // X0
      f32x2 t;
      t = 2.f*a[0] - up2(o.x); w.x = pk2(t);
      t = 2.f*a[1] - up2(o.y); w.y = pk2(t);
      t = 2.f*a[2] - up2(o.z); w.z = pk2(t);
      t = 2.f*a[3] - up2(o.w); w.w = pk2(t);
    } else {
      w.x = pk2(a[0]); w.y = pk2(a[1]); w.z = pk2(a[2]); w.w = pk2(a[3]);
    }
    *(u32x4*)((char*)(XSb + (size_t)dstm*XSN) + doff) = w;
  } else {
    // XI: 2 nodes per 64-thr block, half-wave each; 32 uint2 per row.
    int idx = bx - NN*8;
    int n = idx*2 + (tid>>5), m = tid & 31;
    int e0 = rp[n], e1 = rp[n+1];
    const char* srcp = (const char*)(XIb + (size_t)srcm*XIN) + m*8;
    f32x2 a0 = {0.f,0.f}, a1 = {0.f,0.f};
    for (int e=e0; e<e1; ++e){
      int2 cv = scv[e];
      uint2 d = *(const uint2*)(srcp + ((unsigned)cv.x >> 5));  // (col*8192)>>5 = col*256
      f32x2 vv = {__int_as_float(cv.y), __int_as_float(cv.y)};
      a0 += vv*up2(d.x); a1 += vv*up2(d.y);
    }
    unsigned doff = (unsigned)n*256 + m*8;
    if (CHEB){
      uint2 o = *(const uint2*)((const char*)XIb + doff);
      a0 = 2.f*a0 - up2(o.x); a1 = 2.f*a1 - up2(o.y);
    }
    uint2 wv; wv.x = pk2(a0); wv.y = pk2(a1);
    *(uint2*)((char*)(XIb + (size_t)dstm*XIN) + doff) = wv;
  }
}

// Block = 256 thr (4 waves), one node n per block. A(n) staged to LDS once,
// physical K = m*64+f_state | 320+2m+c | pad. W-frags register-resident per wave
// (wave w owns output tiles t = w + 4*i, i<TW=OT/4).
// MODE 0 (gate): i=0 -> r*state into XS0; i=1 -> u into d_out.
// MODE 1 (cand): c = tanh; new_state = u*state + (1-u)*c into d_out.
template<int OT, int MODE>
__global__ __launch_bounds__(256) void gemm_k(
    u16* __restrict__ XSb, const u16* __restrict__ XIb,
    const u16* __restrict__ Wf, const void* __restrict__ bias,
    const void* __restrict__ state, void* __restrict__ outp,
    const int* __restrict__ flag){
  __shared__ __align__(16) u16 A[64*APITCH];
  int tid = threadIdx.x, n = blockIdx.x;
  int bfflag = *flag;
  #pragma unroll
  for (int m=0;m<5;m++){
    const uint4* src = (const uint4*)(XSb + (size_t)m*XSN + ((size_t)n<<12));
    #pragma unroll
    for (int it=0; it<2; ++it){
      int r = tid + it*256;          // 512 uint4: b = r>>3, f0 = (r&7)*8
      uint4 d = src[r];
      int b = r>>3, f0 = (r&7)*8;
      *(uint4*)&A[b*APITCH + m*64 + f0] = d;
    }
  }
  for (int i=tid; i<320; i+=256){
    int m = i>>6, b = i&63;
    unsigned v = ((const unsigned*)XIb)[(size_t)m*(XIN/2) + n*64 + b];
    *(unsigned*)&A[b*APITCH + 320 + 2*m] = v;
  }
  for (int i=tid; i<64*15; i+=256){
    int b = i/15, j = i - b*15;
    *(unsigned*)&A[b*APITCH + 330 + 2*j] = 0;
  }
  const int TW = OT/4;
  int lane = tid & 63, w = tid >> 6;
  int m16 = lane & 15, q4 = lane >> 4;
  const bf16x8* wp = (const bf16x8*)Wf;
  bf16x8 wfr[11][TW];
  #pragma unroll
  for (int q=0;q<11;q++){
    #pragma unroll
    for (int i=0;i<TW;i++) wfr[q][i] = wp[(q*OT + (w + 4*i))*64 + lane];
  }
  __syncthreads();
  #pragma unroll
  for (int rt4=0; rt4<4; ++rt4){
    const u16* arow = A + (rt4*16 + m16)*APITCH + q4*8;
    f32x4 acc[TW];
    #pragma unroll
    for (int i=0;i<TW;i++) acc[i] = (f32x4){0.f,0.f,0.f,0.f};
    #pragma unroll
    for (int q=0;q<11;q++){
      bf16x8 af = *((const bf16x8*)(arow + q*32));
      #pragma unroll
      for (int i=0;i<TW;i++)
        acc[i] = __builtin_amdgcn_mfma_f32_16x16x32_bf16(af, wfr[q][i], acc[i], 0, 0, 0);
    }
    #pragma unroll
    for (int i=0;i<TW;i++){
      int t = w + 4*i;
      int o = t*16 + m16;
      float bo = loadf(bias, o, bfflag);
      #pragma unroll
      for (int r=0;r<4;r++){
        int b = rt4*16 + q4*4 + r;
        float x = acc[i][r] + bo;
        if (MODE==0){
          float s = 1.f/(1.f + __expf(-x));
          if (i==0){   // o < 64: r-gate -> r*state overwrites XS0(n)
            float st = loadf(state, (size_t)b*(NN*64) + (size_t)n*64 + o, bfflag);
            XSb[((size_t)n<<12) + b*64 + o] = f2bf(s*st);
          } else {     // o >= 64: u stashed in d_out
            size_t idx = (size_t)b*(NN*64) + (size_t)n*64 + (o-64);
            if (bfflag) ((u16*)outp)[idx] = f2bf(s); else ((float*)outp)[idx] = s;
          }
        } else {
          float c = tanhf(x);
          size_t idx = (size_t)b*(NN*64) + (size_t)n*64 + o;
          float uu = bfflag ? bf2f(((const u16*)outp)[idx]) : ((const float*)outp)[idx];
          float st = loadf(state, idx, bfflag);
          float ns = uu*st + (1.f-uu)*c;
          if (bfflag) ((u16*)outp)[idx] = f2bf(ns); else ((float*)outp)[idx] = ns;
        }
      }
    }
  }
}

extern "C" void kernel_launch(void* const* d_in, const int* in_sizes, int n_in,
                              void* d_out, int out_size, void* d_ws, size_t ws_size,
                              hipStream_t stream) {
  const void* inputs = d_in[0];
  const void* state  = d_in[1];
  const int* edges1 = (const int*)d_in[2];
  const void* vals1  = d_in[3];
  const int* edges2 = (const int*)d_in[4];
  const void* vals2  = d_in[5];
  const void* Wg     = d_in[6];
  const void* bg     = d_in[7];
  const void* Wc     = d_in[8];
  const void* bc     = d_in[9];

  char* ws = (char*)d_ws;
  size_t off = 0;
  auto get = [&](size_t bytes)->void*{
    void* p = ws + off; off = (off + bytes + 255) & ~(size_t)255; return p;
  };
  u16* XSb = (u16*)get(5*XSN*2);   // 83.9 MB
  u16* XIb = (u16*)get(5*XIN*2);   // 2.6 MB
  u16* Wfg = (u16*)get(11*8*64*8*2);
  u16* Wfc = (u16*)get(11*4*64*8*2);
  int* cnt  = (int*)get(2*2048*4);
  int* rp   = (int*)get(2*2049*4);
  int* cur  = (int*)get(2*2048*4);
  int* flag = (int*)get(4);
  int2* scv = (int2*)get((size_t)2*EE*8);

  hipMemsetAsync(cnt, 0, 2*2048*4, stream);
  setup1_k<<<513,256,0,stream>>>((const unsigned*)vals1, edges1, edges2, cnt, flag);
  scan2_k<<<2,1024,0,stream>>>(cnt, rp, cur);
  setup2_k<<<776+NN,256,0,stream>>>(edges1, vals1, edges2, vals2, cur, scv,
                                    Wg, Wc, Wfg, Wfc, inputs, state, XSb, XIb, flag);

  dim3 sg(NN*8 + NN/2, 2);
  // gate diffusion
  spmm_k<0><<<sg,64,0,stream>>>(XSb, XIb, rp, scv);
  spmm_k<1><<<sg,64,0,stream>>>(XSb, XIb, rp, scv);
  gemm_k<8,0><<<NN,256,0,stream>>>(XSb, XIb, Wfg, bg, state, d_out, flag);
  // candidate diffusion (XS0 now = r*state, XI0 = inputs)
  spmm_k<0><<<sg,64,0,stream>>>(XSb, XIb, rp, scv);
  spmm_k<1><<<sg,64,0,stream>>>(XSb, XIb, rp, scv);
  gemm_k<4,1><<<NN,256,0,stream>>>(XSb, XIb, Wfc, bc, state, d_out, flag);
}

// Round 13
// 415.410 us; speedup vs baseline: 1.2004x; 1.0597x over previous
//
#include <hip/hip_runtime.h>
#include <stdint.h>

#define NN 2048
#define EE 65536
#define APITCH 360              // LDS K-pitch: 352 used + pad
#define XSN ((size_t)NN*4096)   // elems per XS matrix [N][64][64]
#define XIN ((size_t)NN*128)    // elems per XI matrix [N][64][2]

typedef unsigned short u16;
typedef __bf16 bf16x8 __attribute__((ext_vector_type(8)));
typedef float f32x4 __attribute__((ext_vector_type(4)));
typedef float f32x2 __attribute__((ext_vector_type(2)));
typedef unsigned u32x4 __attribute__((ext_vector_type(4)));

__device__ __forceinline__ float bf2f(u16 h){ return __uint_as_float(((unsigned)h)<<16); }
__device__ __forceinline__ u16 f2bf(float f){
  unsigned u = __float_as_uint(f);
  u += 0x7fffu + ((u>>16)&1u);
  return (u16)(u>>16);
}
__device__ __forceinline__ float loadf(const void* p, size_t i, int bfflag){
  return bfflag ? bf2f(((const u16*)p)[i]) : ((const float*)p)[i];
}
__device__ __forceinline__ f32x2 up2(unsigned u){
  f32x2 r; r.x = __uint_as_float(u<<16); r.y = __uint_as_float(u & 0xffff0000u); return r;
}
__device__ __forceinline__ unsigned pk2(f32x2 t){
  return (unsigned)f2bf(t.x) | ((unsigned)f2bf(t.y)<<16);
}
__device__ __forceinline__ void accv(float v, u32x4 d, f32x2* a){
  f32x2 vv = {v, v};
  a[0] += vv*up2(d.x); a[1] += vv*up2(d.y);
  a[2] += vv*up2(d.z); a[3] += vv*up2(d.w);
}

// Merged: block 0 = dtype probe; blocks 1..256 = hist e1; 257..512 = hist e2.
__global__ void setup1_k(const unsigned* __restrict__ vals,
                         const int* __restrict__ e1, const int* __restrict__ e2,
                         int* __restrict__ cnt, int* __restrict__ flag){
  int b = blockIdx.x, tid = threadIdx.x;
  if (b == 0){
    if (tid < 64){
      unsigned lo = vals[tid] & 0xffffu;
      unsigned long long m = __ballot(lo >= 0x2800u && lo < 0x3D80u);
      if (tid==0) *flag = (__popcll(m) >= 32) ? 1 : 0;
    }
  } else if (b <= 256){
    atomicAdd(&cnt[e1[(b-1)*256 + tid]], 1);
  } else {
    atomicAdd(&cnt[2048 + e2[(b-257)*256 + tid]], 1);
  }
}

__global__ void scan2_k(const int* __restrict__ cntA, int* __restrict__ rpA, int* __restrict__ curA){
  __shared__ int s[1024];
  const int* cnt = cntA + blockIdx.x*2048;
  int* rp  = rpA  + blockIdx.x*2049;
  int* cur = curA + blockIdx.x*2048;
  int t = threadIdx.x;
  int c0 = cnt[2*t], c1 = cnt[2*t+1];
  int ps = c0 + c1;
  s[t] = ps;
  __syncthreads();
  for (int off=1; off<1024; off<<=1){
    int v = (t>=off) ? s[t-off] : 0;
    __syncthreads();
    s[t] += v;
    __syncthreads();
  }
  int excl = s[t] - ps;
  rp[2*t] = excl;  cur[2*t] = excl;
  rp[2*t+1] = excl + c0;  cur[2*t+1] = excl + c0;
  if (t==0) rp[2048] = EE;
}

// Chebyshev weight fold: GEMM consumes [X0, X1, Y2=S X1, X3, Y4=S' X3] with
//   W0' = W0 - W2 - W4,  W2' = 2 W2,  W4' = 2 W4  (W1, W3 unchanged).
__device__ __forceinline__ float wfold(const void* W, int O, int m, int f, int o, int bfflag){
  float v = loadf(W, (size_t)(f*5+m)*O + o, bfflag);
  if (m == 0){
    v -= loadf(W, (size_t)(f*5+2)*O + o, bfflag);
    v -= loadf(W, (size_t)(f*5+4)*O + o, bfflag);
  } else if (m == 2 || m == 4){
    v *= 2.f;
  }
  return v;
}

// Merged post-scan setup. Sections by blockIdx.x:
//  [0,512): scatter (scv.x = col*8192 byte offset, scv.y = f32 bits of val)
//  [512,776): pack W (folded) into MFMA B-frag order (state-first physical K)
//  [776,776+NN): build X0 (XS = state part [N][64][64], XI = input part [N][64][2])
__global__ void setup2_k(const int* __restrict__ e1, const void* __restrict__ v1,
                         const int* __restrict__ e2, const void* __restrict__ v2,
                         int* __restrict__ curA, int2* __restrict__ scvA,
                         const void* __restrict__ Wg, const void* __restrict__ Wc,
                         u16* __restrict__ Wfg, u16* __restrict__ Wfc,
                         const void* __restrict__ inp, const void* __restrict__ st,
                         u16* __restrict__ XSb, u16* __restrict__ XIb,
                         const int* __restrict__ flag){
  int b = blockIdx.x, tid = threadIdx.x;
  int bfflag = *flag;
  if (b < 512){
    const int* rows; const int* cols; const void* vals; int* cur; int2* scv; int e;
    if (b < 256){ rows=e1; cols=e1+EE; vals=v1; cur=curA; scv=scvA; e=b*256+tid; }
    else { rows=e2; cols=e2+EE; vals=v2; cur=curA+2048; scv=scvA+EE; e=(b-256)*256+tid; }
    int r = rows[e];
    int p = atomicAdd(&cur[r], 1);
    int2 cv; cv.x = cols[e] << 13; cv.y = __float_as_int(loadf(vals, e, bfflag));
    scv[p] = cv;
  } else if (b < 776){
    int bb = b - 512;
    const void* W; u16* Wf; int O, OT, i;
    if (bb < 176){ W=Wg; Wf=Wfg; O=128; OT=8; i=bb*256+tid; }
    else { W=Wc; Wf=Wfc; O=64; OT=4; i=(bb-176)*256+tid; }
    int j = i & 7, L = (i>>3)&63, tq = i>>9;
    int t = tq % OT, q = tq / OT;
    int o = t*16 + (L&15);
    int kk = q*32 + (L>>4)*8 + j;
    float v = 0.f;
    if (kk < 320){ int m = kk>>6, f = (kk&63)+2; v = wfold(W, O, m, f, o, bfflag); }
    else if (kk < 330){ int tt = kk-320; int m = tt>>1, f = tt&1; v = wfold(W, O, m, f, o, bfflag); }
    Wf[i] = f2bf(v);
  } else {
    int n = b - 776;
    if (bfflag){
      const uint4* sp = (const uint4*)st;
      uint4* xp = (uint4*)(XSb + (size_t)n*4096);
      #pragma unroll
      for (int it=0; it<2; ++it){
        int r = tid + it*256;
        int bb = r>>3, v4 = r&7;
        xp[r] = sp[(size_t)bb*(NN*8) + (size_t)n*8 + v4];
      }
      if (tid < 64){
        ((unsigned*)XIb)[n*64 + tid] = ((const unsigned*)inp)[(size_t)tid*NN + n];
      }
    } else {
      for (int i=tid; i<4096; i+=256){
        int bb=i>>6, f=i&63;
        XSb[(size_t)n*4096+i] = f2bf(((const float*)st)[(size_t)bb*(NN*64) + n*64 + f]);
      }
      for (int i=tid; i<128; i+=256){
        int bb=i>>1, f=i&1;
        XIb[(size_t)n*128+i] = f2bf(((const float*)inp)[(size_t)bb*(NN*2) + n*2 + f]);
      }
    }
  }
}

// Pure SpMM hop (no Chebyshev combine — weights folded in GEMM).
// HOP=0: dst(1/3) = S X0.  HOP=1: dst(2/4) = S X(1/3).
// R8-proven: 64-thr blocks, 1KB chunks (16B/lane), ch = bx&7 -> XCD pin, 8-edge unroll.
template<int HOP>
__global__ __launch_bounds__(64) void spmm_k(
    u16* __restrict__ XSb, u16* __restrict__ XIb,
    const int* __restrict__ rpA, const int2* __restrict__ scvA){
  int sup = blockIdx.y;
  const int* rp = rpA + sup*2049;
  const int2* scv = scvA + sup*EE;
  const int srcm = HOP ? (sup?3:1) : 0;
  const int dstm = HOP ? (sup?4:2) : (sup?3:1);
  int tid = threadIdx.x;
  int bx = blockIdx.x;
  if (bx < NN*8){
    int ch = bx & 7, n = bx >> 3;
    int e0 = rp[n], e1 = rp[n+1];
    unsigned offB = (unsigned)(ch*64 + tid)*16;
    const char* srcp = (const char*)(XSb + (size_t)srcm*XSN) + offB;
    f32x2 a[4] = {{0.f,0.f},{0.f,0.f},{0.f,0.f},{0.f,0.f}};
    int e = e0;
    for (; e+7 < e1; e += 8){
      const int4* s4 = (const int4*)(scv + e);
      int4 p0 = s4[0], p1 = s4[1], p2 = s4[2], p3 = s4[3];
      u32x4 d0 = *(const u32x4*)(srcp + (unsigned)p0.x);
      u32x4 d1 = *(const u32x4*)(srcp + (unsigned)p0.z);
      u32x4 d2 = *(const u32x4*)(srcp + (unsigned)p1.x);
      u32x4 d3 = *(const u32x4*)(srcp + (unsigned)p1.z);
      u32x4 d4 = *(const u32x4*)(srcp + (unsigned)p2.x);
      u32x4 d5 = *(const u32x4*)(srcp + (unsigned)p2.z);
      u32x4 d6 = *(const u32x4*)(srcp + (unsigned)p3.x);
      u32x4 d7 = *(const u32x4*)(srcp + (unsigned)p3.z);
      accv(__int_as_float(p0.y), d0, a);
      accv(__int_as_float(p0.w), d1, a);
      accv(__int_as_float(p1.y), d2, a);
      accv(__int_as_float(p1.w), d3, a);
      accv(__int_as_float(p2.y), d4, a);
      accv(__int_as_float(p2.w), d5, a);
      accv(__int_as_float(p3.y), d6, a);
      accv(__int_as_float(p3.w), d7, a);
    }
    for (; e < e1; ++e){
      int2 c = scv[e];
      accv(__int_as_float(c.y), *(const u32x4*)(srcp + (unsigned)c.x), a);
    }
    unsigned doff = ((unsigned)n << 13) + offB;
    u32x4 w;
    w.x = pk2(a[0]); w.y = pk2(a[1]); w.z = pk2(a[2]); w.w = pk2(a[3]);
    *(u32x4*)((char*)(XSb + (size_t)dstm*XSN) + doff) = w;
  } else {
    int idx = bx - NN*8;
    int n = idx*2 + (tid>>5), m = tid & 31;
    int e0 = rp[n], e1 = rp[n+1];
    const char* srcp = (const char*)(XIb + (size_t)srcm*XIN) + m*8;
    f32x2 a0 = {0.f,0.f}, a1 = {0.f,0.f};
    for (int e=e0; e<e1; ++e){
      int2 cv = scv[e];
      uint2 d = *(const uint2*)(srcp + ((unsigned)cv.x >> 5));
      f32x2 vv = {__int_as_float(cv.y), __int_as_float(cv.y)};
      a0 += vv*up2(d.x); a1 += vv*up2(d.y);
    }
    unsigned doff = (unsigned)n*256 + m*8;
    uint2 wv; wv.x = pk2(a0); wv.y = pk2(a1);
    *(uint2*)((char*)(XIb + (size_t)dstm*XIN) + doff) = wv;
  }
}

// GATE gemm: 512 thr = 8 waves, one node/block, full-node LDS (45KB).
// TW=1: wave w owns output tile t=w (44 W-VGPRs) -> 4 waves/SIMD occupancy.
// w<4 (o<64): r-gate -> r*state into XS0; w>=4: u into d_out.
__global__ __launch_bounds__(512, 4) void gemm_gate_k(
    u16* __restrict__ XSb, const u16* __restrict__ XIb,
    const u16* __restrict__ Wf, const void* __restrict__ bias,
    const void* __restrict__ state, void* __restrict__ outp,
    const int* __restrict__ flag){
  __shared__ __align__(16) u16 A[64*APITCH];
  int tid = threadIdx.x, n = blockIdx.x;
  int bfflag = *flag;
  {
    int r = tid;                       // 512 uint4 per matrix
    int b = r>>3, f0 = (r&7)*8;
    #pragma unroll
    for (int m=0;m<5;m++){
      uint4 d = ((const uint4*)(XSb + (size_t)m*XSN + ((size_t)n<<12)))[r];
      *(uint4*)&A[b*APITCH + m*64 + f0] = d;
    }
  }
  if (tid < 320){
    int m = tid>>6, b = tid&63;
    unsigned v = ((const unsigned*)XIb)[(size_t)m*(XIN/2) + n*64 + b];
    *(unsigned*)&A[b*APITCH + 320 + 2*m] = v;
  }
  for (int i=tid; i<64*15; i+=512){
    int b = i/15, j = i - b*15;
    *(unsigned*)&A[b*APITCH + 330 + 2*j] = 0;
  }
  int lane = tid & 63, w = tid >> 6;
  int m16 = lane & 15, q4 = lane >> 4;
  const bf16x8* wp = (const bf16x8*)Wf;
  bf16x8 wfr[11];
  #pragma unroll
  for (int q=0;q<11;q++) wfr[q] = wp[(q*8 + w)*64 + lane];
  __syncthreads();
  int o = w*16 + m16;
  float bo = loadf(bias, o, bfflag);
  #pragma unroll
  for (int rt4=0; rt4<4; ++rt4){
    const u16* arow = A + (rt4*16 + m16)*APITCH + q4*8;
    f32x4 acc = (f32x4){0.f,0.f,0.f,0.f};
    #pragma unroll
    for (int q=0;q<11;q++){
      bf16x8 af = *((const bf16x8*)(arow + q*32));
      acc = __builtin_amdgcn_mfma_f32_16x16x32_bf16(af, wfr[q], acc, 0, 0, 0);
    }
    #pragma unroll
    for (int r=0;r<4;r++){
      int b = rt4*16 + q4*4 + r;
      float x = acc[r] + bo;
      float s = 1.f/(1.f + __expf(-x));
      if (w < 4){
        float st = loadf(state, (size_t)b*(NN*64) + (size_t)n*64 + o, bfflag);
        XSb[((size_t)n<<12) + b*64 + o] = f2bf(s*st);
      } else {
        size_t idx = (size_t)b*(NN*64) + (size_t)n*64 + (o-64);
        if (bfflag) ((u16*)outp)[idx] = f2bf(s); else ((float*)outp)[idx] = s;
      }
    }
  }
}

// CAND gemm: 256 thr = 4 waves, HALF node per block (22.5KB LDS), TW=1.
// grid = NN*2: h = bx&1 (row half), n = bx>>1.
// c = tanh; new_state = u*state + (1-u)*c into d_out.
__global__ __launch_bounds__(256, 4) void gemm_cand_k(
    u16* __restrict__ XSb, const u16* __restrict__ XIb,
    const u16* __restrict__ Wf, const void* __restrict__ bias,
    const void* __restrict__ state, void* __restrict__ outp,
    const int* __restrict__ flag){
  __shared__ __align__(16) u16 A[32*APITCH];
  int tid = threadIdx.x;
  int h = blockIdx.x & 1, n = blockIdx.x >> 1;
  int bfflag = *flag;
  {
    int r = tid;                       // 256 uint4 per matrix half
    int bl = r>>3, f0 = (r&7)*8;
    #pragma unroll
    for (int m=0;m<5;m++){
      uint4 d = ((const uint4*)(XSb + (size_t)m*XSN + ((size_t)n<<12)))[h*256 + r];
      *(uint4*)&A[bl*APITCH + m*64 + f0] = d;
    }
  }
  if (tid < 160){
    int m = tid>>5, bl = tid&31;
    unsigned v = ((const unsigned*)XIb)[(size_t)m*(XIN/2) + n*64 + h*32 + bl];
    *(unsigned*)&A[bl*APITCH + 320 + 2*m] = v;
  }
  for (int i=tid; i<32*15; i+=256){
    int bl = i/15, j = i - bl*15;
    *(unsigned*)&A[bl*APITCH + 330 + 2*j] = 0;
  }
  int lane = tid & 63, w = tid >> 6;
  int m16 = lane & 15, q4 = lane >> 4;
  const bf16x8* wp = (const bf16x8*)Wf;
  bf16x8 wfr[11];
  #pragma unroll
  for (int q=0;q<11;q++) wfr[q] = wp[(q*4 + w)*64 + lane];
  __syncthreads();
  int o = w*16 + m16;
  float bo = loadf(bias, o, bfflag);
  #pragma unroll
  for (int rt2=0; rt2<2; ++rt2){
    const u16* arow = A + (rt2*16 + m16)*APITCH + q4*8;
    f32x4 acc = (f32x4){0.f,0.f,0.f,0.f};
    #pragma unroll
    for (int q=0;q<11;q++){
      bf16x8 af = *((const bf16x8*)(arow + q*32));
      acc = __builtin_amdgcn_mfma_f32_16x16x32_bf16(af, wfr[q], acc, 0, 0, 0);
    }
    #pragma unroll
    for (int r=0;r<4;r++){
      int b = h*32 + rt2*16 + q4*4 + r;
      float x = acc[r] + bo;
      float c = tanhf(x);
      size_t idx = (size_t)b*(NN*64) + (size_t)n*64 + o;
      float uu = bfflag ? bf2f(((const u16*)outp)[idx]) : ((const float*)outp)[idx];
      float st = loadf(state, idx, bfflag);
      float ns = uu*st + (1.f-uu)*c;
      if (bfflag) ((u16*)outp)[idx] = f2bf(ns); else ((float*)outp)[idx] = ns;
    }
  }
}

extern "C" void kernel_launch(void* const* d_in, const int* in_sizes, int n_in,
                              void* d_out, int out_size, void* d_ws, size_t ws_size,
                              hipStream_t stream) {
  const void* inputs = d_in[0];
  const void* state  = d_in[1];
  const int* edges1 = (const int*)d_in[2];
  const void* vals1  = d_in[3];
  const int* edges2 = (const int*)d_in[4];
  const void* vals2  = d_in[5];
  const void* Wg     = d_in[6];
  const void* bg     = d_in[7];
  const void* Wc     = d_in[8];
  const void* bc     = d_in[9];

  char* ws = (char*)d_ws;
  size_t off = 0;
  auto get = [&](size_t bytes)->void*{
    void* p = ws + off; off = (off + bytes + 255) & ~(size_t)255; return p;
  };
  u16* XSb = (u16*)get(5*XSN*2);   // 83.9 MB
  u16* XIb = (u16*)get(5*XIN*2);   // 2.6 MB
  u16* Wfg = (u16*)get(11*8*64*8*2);
  u16* Wfc = (u16*)get(11*4*64*8*2);
  int* cnt  = (int*)get(2*2048*4);
  int* rp   = (int*)get(2*2049*4);
  int* cur  = (int*)get(2*2048*4);
  int* flag = (int*)get(4);
  int2* scv = (int2*)get((size_t)2*EE*8);

  hipMemsetAsync(cnt, 0, 2*2048*4, stream);
  setup1_k<<<513,256,0,stream>>>((const unsigned*)vals1, edges1, edges2, cnt, flag);
  scan2_k<<<2,1024,0,stream>>>(cnt, rp, cur);
  setup2_k<<<776+NN,256,0,stream>>>(edges1, vals1, edges2, vals2, cur, scv,
                                    Wg, Wc, Wfg, Wfc, inputs, state, XSb, XIb, flag);

  dim3 sg(NN*8 + NN/2, 2);
  // gate diffusion (hop2 is a pure SpMM; Chebyshev combine folded into W)
  spmm_k<0><<<sg,64,0,stream>>>(XSb, XIb, rp, scv);
  spmm_k<1><<<sg,64,0,stream>>>(XSb, XIb, rp, scv);
  gemm_gate_k<<<NN,512,0,stream>>>(XSb, XIb, Wfg, bg, state, d_out, flag);
  // candidate diffusion (XS0 now = r*state, XI0 = inputs)
  spmm_k<0><<<sg,64,0,stream>>>(XSb, XIb, rp, scv);
  spmm_k<1><<<sg,64,0,stream>>>(XSb, XIb, rp, scv);
  gemm_cand_k<<<NN*2,256,0,stream>>>(XSb, XIb, Wfc, bc, state, d_out, flag);
}